// Round 3
// baseline (443.993 us; speedup 1.0000x reference)
//
#include <hip/hip_runtime.h>
#include <hip/hip_bf16.h>

#define B_  2048
#define L_  200
#define D_  128
#define H0_ 80
#define H1_ 40

typedef __attribute__((ext_vector_type(8))) short short8;
typedef __attribute__((ext_vector_type(4))) float floatx4;

__device__ __forceinline__ short f2bf(float f) {
    unsigned u = __float_as_uint(f);
    u += 0x7fffu + ((u >> 16) & 1u);   // round-to-nearest-even
    return (short)(u >> 16);
}
__device__ __forceinline__ float bf2f(short s) {
    return __uint_as_float(((unsigned)(unsigned short)s) << 16);
}

// ws layout (bytes):
//   [0, 41943040)            bf16 W0effT  [B][80][128]
//   [41943040, 41952256)     bf16 W1T     [48][96]  (zero-padded)
//   [41952256, 42607616)     f32  beff    [B][80]
#define W1T_SOFF  (B_ * H0_ * D_)          // short offset
#define BEFF_FOFF ((B_ * H0_ * D_ + 48 * 96) / 2)  // float offset

// ---------------- prep: per-b effective weights (throughput kernel) --------
// Layer0 factorization: feat@W0 = hist@(W0a+W0c+diag(tgt)W0d) + [tgt@(W0b-W0c)+b0]
__global__ __launch_bounds__(256, 2) void prep_kernel(
    const float* __restrict__ tgt, const float* __restrict__ W0,
    const float* __restrict__ b0, const float* __restrict__ W1,
    short* __restrict__ w0t, short* __restrict__ w1t, float* __restrict__ beff)
{
    __shared__ float w0s[H0_][130];   // fp32 (W0a+W0c), [h][d], pad->bank-clean
    __shared__ short w0d[H0_][130];   // bf16 W0d
    __shared__ float tgs[D_];
    __shared__ float red2[2][H0_];

    const int tid = threadIdx.x;
    for (int i = tid; i < D_ * H0_; i += 256) {      // i = d*80+h
        int d = i / H0_, h = i - d * H0_;
        w0s[h][d] = W0[i] + W0[256 * H0_ + i];
        w0d[h][d] = f2bf(W0[384 * H0_ + i]);
    }
    if (blockIdx.x == 0) {
        for (int i = tid; i < 48 * 96; i += 256) {
            int n = i / 96, k = i - n * 96;
            w1t[i] = (n < H1_ && k < H0_) ? f2bf(W1[k * H1_ + n]) : (short)0;
        }
    }
    for (int bb = 0; bb < 4; ++bb) {
        const int b = blockIdx.x * 4 + bb;
        __syncthreads();                              // tgs/red2 reuse + staging
        if (tid < D_) tgs[tid] = tgt[(size_t)b * D_ + tid];
        __syncthreads();
        short* outp = w0t + (size_t)b * H0_ * D_;
        for (int i = tid; i < H0_ * D_; i += 256) {   // i = h*128+d
            int h = i >> 7, d = i & 127;
            outp[i] = f2bf(w0s[h][d] + tgs[d] * bf2f(w0d[h][d]));
        }
        if (tid < 160) {
            int seg = tid / H0_, h = tid - seg * H0_;
            float s = 0.f;
            #pragma unroll 8
            for (int dd = 0; dd < 64; ++dd) {
                int d = seg * 64 + dd;
                s += tgs[d] * (W0[(128 + d) * H0_ + h] - W0[(256 + d) * H0_ + h]);
            }
            red2[seg][h] = s;
        }
        __syncthreads();
        if (tid < H0_)
            beff[(size_t)b * H0_ + tid] = b0[tid] + red2[0][tid] + red2[1][tid];
    }
}

// ---------------- main: MFMA layers + softmax + weighted sum ----------------
__global__ __launch_bounds__(256, 4) void din_main(
    const float* __restrict__ hist, const int* __restrict__ mask,
    const float* __restrict__ b1, const float* __restrict__ W2,
    const float* __restrict__ b2,
    const short* __restrict__ w0t, const short* __restrict__ w1t,
    const float* __restrict__ beff, float* __restrict__ out)
{
    __shared__ __align__(16) short h0t[4][16][104];  // per-wave h0 tile, k>=80 zero
    __shared__ float beffs[H0_];
    __shared__ float b1w2[2][48];
    __shared__ float scores[208];
    __shared__ float attns[L_];
    __shared__ float partial[2][D_];
    __shared__ float red[8];

    const int tid = threadIdx.x;
    const int b   = blockIdx.x;
    float* ui_out   = out + (size_t)b * D_;
    float* attn_out = out + (size_t)B_ * D_ + (size_t)b * L_;

    const float b2v = b2[0];
    int mv = 1;
    if (tid < L_) mv = mask[(size_t)b * L_ + tid];   // prefetch early

    if (tid < H0_) beffs[tid] = beff[(size_t)b * H0_ + tid];
    if (tid < 48) {
        b1w2[0][tid] = (tid < H1_) ? b1[tid] : 0.f;
        b1w2[1][tid] = (tid < H1_) ? W2[tid] : 0.f;
    }
    for (int i = tid; i < 4 * 16 * 104 / 2; i += 256) ((int*)h0t)[i] = 0;
    __syncthreads();

    const int wave = tid >> 6, lane = tid & 63;
    const int col = lane & 15, quad = lane >> 4;
    const short* w0b = w0t + (size_t)b * H0_ * D_;

    for (int mt = wave; mt < 13; mt += 4) {
        const int m0 = mt * 16;
        int mrow = m0 + col; if (mrow > L_ - 1) mrow = L_ - 1;
        const float* ap = hist + ((size_t)b * L_ + mrow) * D_ + quad * 8;

        short8 afrag[4];
        #pragma unroll
        for (int ks = 0; ks < 4; ++ks) {
            floatx4 x = *(const floatx4*)(ap + ks * 32);
            floatx4 y = *(const floatx4*)(ap + ks * 32 + 4);
            short8 a;
            a[0] = f2bf(x[0]); a[1] = f2bf(x[1]); a[2] = f2bf(x[2]); a[3] = f2bf(x[3]);
            a[4] = f2bf(y[0]); a[5] = f2bf(y[1]); a[6] = f2bf(y[2]); a[7] = f2bf(y[3]);
            afrag[ks] = a;
        }

        // layer 0: B-frags straight from global (L2-hot W0effT[b])
        floatx4 c0[5];
        #pragma unroll
        for (int nt = 0; nt < 5; ++nt) c0[nt] = (floatx4)0.f;
        const short* bp = w0b + col * D_ + quad * 8;
        #pragma unroll
        for (int ks = 0; ks < 4; ++ks) {
            #pragma unroll
            for (int nt = 0; nt < 5; ++nt) {
                short8 bfr = *(const short8*)(bp + nt * 16 * D_ + ks * 32);
                c0[nt] = __builtin_amdgcn_mfma_f32_16x16x32_bf16(afrag[ks], bfr, c0[nt], 0, 0, 0);
            }
        }
        #pragma unroll
        for (int nt = 0; nt < 5; ++nt) {
            #pragma unroll
            for (int r = 0; r < 4; ++r) {
                float v = c0[nt][r] + beffs[nt * 16 + col];
                v = v > 0.f ? v : 0.f;
                h0t[wave][quad * 4 + r][nt * 16 + col] = f2bf(v);
            }
        }

        // layer 1: A from wave-private LDS tile, B-frags from global W1T (L2-hot)
        floatx4 c1[3];
        #pragma unroll
        for (int nt = 0; nt < 3; ++nt) c1[nt] = (floatx4)0.f;
        const short* wp = w1t + col * 96 + quad * 8;
        #pragma unroll
        for (int ks = 0; ks < 3; ++ks) {
            short8 a1 = *(const short8*)&h0t[wave][col][ks * 32 + quad * 8];
            #pragma unroll
            for (int nt = 0; nt < 3; ++nt) {
                short8 bfr = *(const short8*)(wp + nt * 16 * 96 + ks * 32);
                c1[nt] = __builtin_amdgcn_mfma_f32_16x16x32_bf16(a1, bfr, c1[nt], 0, 0, 0);
            }
        }
        // layer 2 + reduce over 16 col-lanes
        float s4[4] = {0.f, 0.f, 0.f, 0.f};
        #pragma unroll
        for (int nt = 0; nt < 3; ++nt) {
            float bb = b1w2[0][nt * 16 + col];
            float ww = b1w2[1][nt * 16 + col];
            #pragma unroll
            for (int r = 0; r < 4; ++r) {
                float v = c1[nt][r] + bb;
                v = v > 0.f ? v : 0.f;
                s4[r] += v * ww;
            }
        }
        #pragma unroll
        for (int r = 0; r < 4; ++r) {
            s4[r] += __shfl_xor(s4[r], 1, 16);
            s4[r] += __shfl_xor(s4[r], 2, 16);
            s4[r] += __shfl_xor(s4[r], 4, 16);
            s4[r] += __shfl_xor(s4[r], 8, 16);
        }
        if (col == 0) {
            #pragma unroll
            for (int r = 0; r < 4; ++r)
                scores[m0 + quad * 4 + r] = s4[r] + b2v;
        }
    }
    __syncthreads();

    // ---- softmax over L with mask ----
    float sc;
    if (tid < L_) {
        sc = scores[tid];
        if (mv == 0) sc -= 1e9f;
    } else {
        sc = -3.0e38f;
    }
    float m = sc;
    #pragma unroll
    for (int off = 32; off >= 1; off >>= 1) m = fmaxf(m, __shfl_xor(m, off, 64));
    int wid = tid >> 6;
    if ((tid & 63) == 0) red[wid] = m;
    __syncthreads();
    m = fmaxf(fmaxf(red[0], red[1]), fmaxf(red[2], red[3]));
    float e = (tid < L_) ? __expf(sc - m) : 0.f;
    float s = e;
    #pragma unroll
    for (int off = 32; off >= 1; off >>= 1) s += __shfl_xor(s, off, 64);
    if ((tid & 63) == 0) red[4 + wid] = s;
    __syncthreads();
    s = red[4] + red[5] + red[6] + red[7];
    float inv = 1.0f / s;
    if (tid < L_) {
        float av = e * inv;
        attns[tid] = av;
        attn_out[tid] = av;
    }
    __syncthreads();

    // ---- user_interest ----
    {
        const int half = tid >> 7, d = tid & 127;
        const float* hb = hist + ((size_t)b * L_ + half * 100) * D_ + d;
        float acc = 0.f;
        #pragma unroll 10
        for (int l = 0; l < 100; ++l)
            acc = fmaf(attns[half * 100 + l], hb[(size_t)l * D_], acc);
        partial[half][d] = acc;
    }
    __syncthreads();
    if (tid < D_) ui_out[tid] = partial[0][tid] + partial[1][tid];
}

extern "C" void kernel_launch(void* const* d_in, const int* in_sizes, int n_in,
                              void* d_out, int out_size, void* d_ws, size_t ws_size,
                              hipStream_t stream) {
    const float* hist = (const float*)d_in[0];
    const float* tgt  = (const float*)d_in[1];
    const int*   mask = (const int*)d_in[2];
    const float* W0   = (const float*)d_in[3];
    const float* b0   = (const float*)d_in[4];
    const float* W1   = (const float*)d_in[5];
    const float* b1   = (const float*)d_in[6];
    const float* W2   = (const float*)d_in[7];
    const float* b2   = (const float*)d_in[8];

    short* w0t = (short*)d_ws;
    short* w1t = (short*)d_ws + W1T_SOFF;
    float* beff = (float*)d_ws + BEFF_FOFF;

    prep_kernel<<<512, 256, 0, stream>>>(tgt, W0, b0, W1, w0t, w1t, beff);
    din_main<<<B_, 256, 0, stream>>>(hist, mask, b1, W2, b2, w0t, w1t, beff,
                                     (float*)d_out);
}

// Round 4
// 426.240 us; speedup vs baseline: 1.0417x; 1.0417x over previous
//
#include <hip/hip_runtime.h>
#include <hip/hip_bf16.h>

#define B_  2048
#define L_  200
#define D_  128
#define H0_ 80
#define H1_ 40

typedef __attribute__((ext_vector_type(8))) short short8;
typedef __attribute__((ext_vector_type(4))) short short4v;
typedef __attribute__((ext_vector_type(2))) short short2v;
typedef __attribute__((ext_vector_type(4))) float floatx4;

__device__ __forceinline__ short f2bf(float f) {
    unsigned u = __float_as_uint(f);
    u += 0x7fffu + ((u >> 16) & 1u);   // round-to-nearest-even
    return (short)(u >> 16);
}
__device__ __forceinline__ float bf2f(short s) {
    return __uint_as_float(((unsigned)(unsigned short)s) << 16);
}

// ws layout:
//   bf16 w0t [B][80][128]   @ short offset 0          (41,943,040 B)
//   bf16 w1t [48][96]       @ short offset B*80*128   (9,216 B)
//   f32  beff [B][80]       after that                (655,360 B)
#define W1T_SOFF  (B_ * H0_ * D_)
#define BEFF_FOFF ((B_ * H0_ * D_ + 48 * 96) / 2)

// ---------------- prep: per-b effective weights -----------------------------
// feat@W0 = hist@(W0a+W0c+diag(tgt)W0d) + [tgt@(W0b-W0c)+b0]
__global__ __launch_bounds__(256, 2) void prep_kernel(
    const float* __restrict__ tgt, const float* __restrict__ W0,
    const float* __restrict__ b0, const float* __restrict__ W1,
    short* __restrict__ w0t, short* __restrict__ w1t, float* __restrict__ beff)
{
    __shared__ short w0s[H0_][132];    // bf16(W0a+W0c) [h][d]
    __shared__ short w0d[H0_][132];    // bf16(W0d)     [h][d]
    __shared__ short w0bc[D_][84];     // bf16(W0b-W0c) [d][h]
    __shared__ float tgs[D_];
    __shared__ float red3[3][H0_];

    const int tid = threadIdx.x;
    for (int i = tid; i < D_ * H0_; i += 256) {   // i = d*80 + h
        int d = i / H0_, h = i - d * H0_;
        float va = W0[i];
        float vb = W0[128 * H0_ + i];
        float vc = W0[256 * H0_ + i];
        float vd = W0[384 * H0_ + i];
        w0s[h][d]  = f2bf(va + vc);
        w0d[h][d]  = f2bf(vd);
        w0bc[d][h] = f2bf(vb - vc);
    }
    if (blockIdx.x == 0) {
        for (int i = tid; i < 48 * 96; i += 256) {
            int n = i / 96, k = i - n * 96;
            w1t[i] = (n < H1_ && k < H0_) ? f2bf(W1[k * H1_ + n]) : (short)0;
        }
    }
    for (int bb = 0; bb < 4; ++bb) {
        const int b = blockIdx.x * 4 + bb;
        __syncthreads();                           // staging + red3 reuse
        if (tid < D_) tgs[tid] = tgt[(size_t)b * D_ + tid];
        __syncthreads();
        short* outp = w0t + (size_t)b * H0_ * D_;
        for (int i = tid; i < H0_ * D_ / 2; i += 256) {   // short2 pairs
            int h = i >> 6, d2 = (i & 63) * 2;
            float t0 = tgs[d2], t1 = tgs[d2 + 1];
            float lo = bf2f(w0s[h][d2])     + t0 * bf2f(w0d[h][d2]);
            float hi = bf2f(w0s[h][d2 + 1]) + t1 * bf2f(w0d[h][d2 + 1]);
            short2v p; p[0] = f2bf(lo); p[1] = f2bf(hi);
            *(short2v*)(outp + h * D_ + d2) = p;
        }
        if (tid < 240) {
            int seg = tid / H0_, h = tid - seg * H0_;
            int d0 = seg * 43;
            int d1 = (seg == 2) ? D_ : d0 + 43;
            float s = 0.f;
            #pragma unroll 8
            for (int d = d0; d < d1; ++d)
                s += tgs[d] * bf2f(w0bc[d][h]);
            red3[seg][h] = s;
        }
        __syncthreads();
        if (tid < H0_)
            beff[(size_t)b * H0_ + tid] = b0[tid] + red3[0][tid] + red3[1][tid] + red3[2][tid];
    }
}

// ---------------- scores: MFMA layers 0/1 + layer-2 reduce ------------------
__global__ __launch_bounds__(256, 3) void score_kernel(
    const float* __restrict__ hist,
    const short* __restrict__ w0t, const short* __restrict__ w1t,
    const float* __restrict__ beff, const float* __restrict__ b1,
    const float* __restrict__ W2, const float* __restrict__ b2,
    float* __restrict__ out)
{
    __shared__ __align__(16) short w0L[H0_][136];   // stride mult of 8 shorts
    __shared__ __align__(16) short w1L[48][104];
    __shared__ __align__(16) short h0t[4][16][104]; // per-wave, k>=80 zeroed

    const int tid = threadIdx.x;
    const int b   = blockIdx.x;
    const int wave = tid >> 6, lane = tid & 63;
    const int col = lane & 15, quad = lane >> 4;
    float* scores = out + (size_t)B_ * D_ + (size_t)b * L_;  // attn slot

    // per-lane constants (L2-hot gathers, no LDS dependency)
    float beffr[5], b1r[3], w2r[3];
    #pragma unroll
    for (int nt = 0; nt < 5; ++nt) beffr[nt] = beff[(size_t)b * H0_ + nt * 16 + col];
    #pragma unroll
    for (int nt = 0; nt < 3; ++nt) {
        int h = nt * 16 + col;
        b1r[nt] = (h < H1_) ? b1[h] : 0.f;
        w2r[nt] = (h < H1_) ? W2[h] : 0.f;
    }
    const float b2v = b2[0];

    // stage w0t[b] -> w0L (coalesced dwordx4 both sides)
    const short* w0g = w0t + (size_t)b * H0_ * D_;
    #pragma unroll
    for (int k = 0; k < 5; ++k) {
        int i = tid + k * 256;                  // short8 chunk, 1280 total
        int row = i >> 4, c0 = (i & 15) * 8;
        *(short8*)&w0L[row][c0] = *(const short8*)(w0g + i * 8);
    }
    // stage w1t -> w1L (short4 chunks, 1152 total)
    for (int i = tid; i < 1152; i += 256) {
        int e0 = i * 4;
        int row = e0 / 96, c0 = e0 - row * 96;
        *(short4v*)&w1L[row][c0] = *(const short4v*)(w1t + e0);
    }
    // zero k-tail cols 80..95 of h0t
    for (int i = tid; i < 128; i += 256) {
        int w = i >> 5, row = (i >> 1) & 15, c0 = 80 + (i & 1) * 8;
        *(short8*)&h0t[w][row][c0] = (short8)0;
    }
    __syncthreads();

    // ---- mt loop with A double-buffer ----
    int mt = wave;
    {
        int mr = mt * 16 + col; if (mr > L_ - 1) mr = L_ - 1;
        const float* ap = hist + ((size_t)b * L_ + mr) * D_ + quad * 8;
        floatx4 A[8];
        #pragma unroll
        for (int u = 0; u < 8; ++u) A[u] = *(const floatx4*)(ap + (u >> 1) * 32 + (u & 1) * 4);

        for (; mt < 13; mt += 4) {
            floatx4 An[8];
            int mtn = mt + 4;
            if (mtn < 13) {
                int mrn = mtn * 16 + col; if (mrn > L_ - 1) mrn = L_ - 1;
                const float* apn = hist + ((size_t)b * L_ + mrn) * D_ + quad * 8;
                #pragma unroll
                for (int u = 0; u < 8; ++u) An[u] = *(const floatx4*)(apn + (u >> 1) * 32 + (u & 1) * 4);
            }
            // fp32 -> bf16 A-frags
            short8 afrag[4];
            #pragma unroll
            for (int ks = 0; ks < 4; ++ks) {
                short8 a;
                a[0] = f2bf(A[2 * ks][0]); a[1] = f2bf(A[2 * ks][1]);
                a[2] = f2bf(A[2 * ks][2]); a[3] = f2bf(A[2 * ks][3]);
                a[4] = f2bf(A[2 * ks + 1][0]); a[5] = f2bf(A[2 * ks + 1][1]);
                a[6] = f2bf(A[2 * ks + 1][2]); a[7] = f2bf(A[2 * ks + 1][3]);
                afrag[ks] = a;
            }

            // layer 0: 16x80, K=128, B-frags from LDS
            floatx4 c0[5];
            #pragma unroll
            for (int nt = 0; nt < 5; ++nt) c0[nt] = (floatx4)0.f;
            #pragma unroll
            for (int ks = 0; ks < 4; ++ks) {
                #pragma unroll
                for (int nt = 0; nt < 5; ++nt) {
                    short8 bfr = *(const short8*)&w0L[nt * 16 + col][ks * 32 + quad * 8];
                    c0[nt] = __builtin_amdgcn_mfma_f32_16x16x32_bf16(afrag[ks], bfr, c0[nt], 0, 0, 0);
                }
            }
            #pragma unroll
            for (int nt = 0; nt < 5; ++nt) {
                #pragma unroll
                for (int r = 0; r < 4; ++r) {
                    float v = c0[nt][r] + beffr[nt];
                    v = v > 0.f ? v : 0.f;
                    h0t[wave][quad * 4 + r][nt * 16 + col] = f2bf(v);
                }
            }

            // layer 1: 16x40(+8 pad), K=80(+16 zero)
            floatx4 c1[3];
            #pragma unroll
            for (int nt = 0; nt < 3; ++nt) c1[nt] = (floatx4)0.f;
            #pragma unroll
            for (int ks = 0; ks < 3; ++ks) {
                short8 a1 = *(const short8*)&h0t[wave][col][ks * 32 + quad * 8];
                #pragma unroll
                for (int nt = 0; nt < 3; ++nt) {
                    short8 bfr = *(const short8*)&w1L[nt * 16 + col][ks * 32 + quad * 8];
                    c1[nt] = __builtin_amdgcn_mfma_f32_16x16x32_bf16(a1, bfr, c1[nt], 0, 0, 0);
                }
            }
            // layer 2 + 16-lane reduce
            float s4[4] = {0.f, 0.f, 0.f, 0.f};
            #pragma unroll
            for (int nt = 0; nt < 3; ++nt) {
                #pragma unroll
                for (int r = 0; r < 4; ++r) {
                    float v = c1[nt][r] + b1r[nt];
                    v = v > 0.f ? v : 0.f;
                    s4[r] += v * w2r[nt];
                }
            }
            #pragma unroll
            for (int r = 0; r < 4; ++r) {
                s4[r] += __shfl_xor(s4[r], 1, 16);
                s4[r] += __shfl_xor(s4[r], 2, 16);
                s4[r] += __shfl_xor(s4[r], 4, 16);
                s4[r] += __shfl_xor(s4[r], 8, 16);
            }
            if (col == 0) {
                #pragma unroll
                for (int r = 0; r < 4; ++r) {
                    int m = mt * 16 + quad * 4 + r;
                    if (m < L_) scores[m] = s4[r] + b2v;
                }
            }
            #pragma unroll
            for (int u = 0; u < 8; ++u) A[u] = An[u];
        }
    }
}

// ---------------- softmax + weighted sum (streaming, full occupancy) --------
__global__ __launch_bounds__(256, 8) void attn_kernel(
    const float* __restrict__ hist, const int* __restrict__ mask,
    float* __restrict__ out)
{
    __shared__ float attns[L_];
    __shared__ float red[8];
    __shared__ float p0[D_];
    __shared__ float p1[D_];

    const int tid = threadIdx.x;
    const int b   = blockIdx.x;
    float* attn_out = out + (size_t)B_ * D_ + (size_t)b * L_;  // holds scores
    float* ui_out   = out + (size_t)b * D_;

    float sc = -3.0e38f;
    if (tid < L_) {
        sc = attn_out[tid];
        if (mask[(size_t)b * L_ + tid] == 0) sc -= 1e9f;
    }
    float m = sc;
    #pragma unroll
    for (int off = 32; off >= 1; off >>= 1) m = fmaxf(m, __shfl_xor(m, off, 64));
    int wid = tid >> 6;
    if ((tid & 63) == 0) red[wid] = m;
    __syncthreads();
    m = fmaxf(fmaxf(red[0], red[1]), fmaxf(red[2], red[3]));
    float e = (tid < L_) ? __expf(sc - m) : 0.f;
    float s = e;
    #pragma unroll
    for (int off = 32; off >= 1; off >>= 1) s += __shfl_xor(s, off, 64);
    if ((tid & 63) == 0) red[4 + wid] = s;
    __syncthreads();
    s = red[4] + red[5] + red[6] + red[7];
    float inv = 1.0f / s;
    float av = e * inv;
    if (tid < L_) {
        attns[tid] = av;
        attn_out[tid] = av;     // safe: all reads were before the barriers
    }
    __syncthreads();

    // user_interest: deep pipeline, 25 loads in flight
    const int half = tid >> 7, d = tid & 127;
    const float* hb = hist + ((size_t)b * L_ + half * 100) * D_ + d;
    float acc = 0.f;
    #pragma unroll 25
    for (int l = 0; l < 100; ++l)
        acc = fmaf(attns[half * 100 + l], hb[(size_t)l * D_], acc);
    if (half) p1[d] = acc; else p0[d] = acc;
    __syncthreads();
    if (tid < D_) ui_out[tid] = p0[tid] + p1[tid];
}

extern "C" void kernel_launch(void* const* d_in, const int* in_sizes, int n_in,
                              void* d_out, int out_size, void* d_ws, size_t ws_size,
                              hipStream_t stream) {
    const float* hist = (const float*)d_in[0];
    const float* tgt  = (const float*)d_in[1];
    const int*   mask = (const int*)d_in[2];
    const float* W0   = (const float*)d_in[3];
    const float* b0   = (const float*)d_in[4];
    const float* W1   = (const float*)d_in[5];
    const float* b1   = (const float*)d_in[6];
    const float* W2   = (const float*)d_in[7];
    const float* b2   = (const float*)d_in[8];

    short* w0t  = (short*)d_ws;
    short* w1t  = (short*)d_ws + W1T_SOFF;
    float* beff = (float*)d_ws + BEFF_FOFF;

    prep_kernel<<<512, 256, 0, stream>>>(tgt, W0, b0, W1, w0t, w1t, beff);
    score_kernel<<<B_, 256, 0, stream>>>(hist, w0t, w1t, beff, b1, W2, b2,
                                         (float*)d_out);
    attn_kernel<<<B_, 256, 0, stream>>>(hist, mask, (float*)d_out);
}

// Round 5
// 389.665 us; speedup vs baseline: 1.1394x; 1.0939x over previous
//
#include <hip/hip_runtime.h>
#include <hip/hip_bf16.h>

#define B_  2048
#define L_  200
#define D_  128
#define H0_ 80
#define H1_ 40
#define NT_ 25600   // (B_*L_)/16 tiles, exact

typedef __attribute__((ext_vector_type(8))) short short8;
typedef __attribute__((ext_vector_type(4))) float floatx4;

__device__ __forceinline__ short f2bf(float f) {
    unsigned u = __float_as_uint(f);
    u += 0x7fffu + ((u >> 16) & 1u);   // round-to-nearest-even
    return (short)(u >> 16);
}
__device__ __forceinline__ float bf2f(short s) {
    return __uint_as_float(((unsigned)(unsigned short)s) << 16);
}

// ws layout (shorts): Bg [80][256] @0 | w1t [48][96] @20480 | beff2 f32 [B][80] @float 12544
#define W1T_SOFF  20480
#define BEFF_FOFF 12544

// ---------------- prep: shared bf16 weights + per-b bias --------------------
// feat@W0 = hist@(W0a+W0c) + (hist.*tgt)@W0d + [tgt@(W0b-W0c)+b0]
__global__ __launch_bounds__(256, 2) void prep_kernel(
    const float* __restrict__ tgt, const float* __restrict__ W0,
    const float* __restrict__ b0, const float* __restrict__ W1,
    short* __restrict__ Bg, short* __restrict__ w1t, float* __restrict__ beff2)
{
    __shared__ short w0bc[D_][84];    // bf16(W0b-W0c) [d][h]
    __shared__ float tgs[D_];
    __shared__ float red3[3][H0_];

    const int tid = threadIdx.x;
    for (int i = tid; i < D_ * H0_; i += 256) {   // i = d*80+h, coalesced
        int d = i / H0_, h = i - d * H0_;
        w0bc[d][h] = f2bf(W0[128 * H0_ + i] - W0[256 * H0_ + i]);
    }
    if (blockIdx.x == 0) {
        for (int i = tid; i < H0_ * 256; i += 256) {   // i = h*256+k
            int h = i >> 8, k = i & 255;
            float v = (k < 128) ? (W0[k * H0_ + h] + W0[(256 + k) * H0_ + h])
                                : W0[(384 + (k - 128)) * H0_ + h];
            Bg[i] = f2bf(v);
        }
        for (int i = tid; i < 48 * 96; i += 256) {
            int n = i / 96, k = i - n * 96;
            w1t[i] = (n < H1_ && k < H0_) ? f2bf(W1[k * H1_ + n]) : (short)0;
        }
    }
    for (int bb = 0; bb < 8; ++bb) {
        const int b = blockIdx.x * 8 + bb;
        __syncthreads();
        if (tid < D_) tgs[tid] = tgt[(size_t)b * D_ + tid];
        __syncthreads();
        if (tid < 240) {
            int seg = tid / H0_, h = tid - seg * H0_;
            int d0 = seg * 43, d1 = (seg == 2) ? D_ : d0 + 43;
            float s = 0.f;
            #pragma unroll 8
            for (int d = d0; d < d1; ++d) s += tgs[d] * bf2f(w0bc[d][h]);
            red3[seg][h] = s;
        }
        __syncthreads();
        if (tid < H0_)
            beff2[(size_t)b * H0_ + tid] = b0[tid] + red3[0][tid] + red3[1][tid] + red3[2][tid];
    }
}

// ---------------- scores: one shared GEMM, streaming tiles ------------------
__global__ __launch_bounds__(256, 2) void score_kernel(
    const float* __restrict__ hist, const float* __restrict__ tgt,
    const short* __restrict__ Bg, const short* __restrict__ w1t,
    const float* __restrict__ beff2, const float* __restrict__ b1,
    const float* __restrict__ W2, const float* __restrict__ b2,
    float* __restrict__ out)
{
    __shared__ __align__(16) short Bs[H0_][264];     // [h][k], k<128 W0ac, k>=128 W0d
    __shared__ __align__(16) short h0t[4][16][104];  // wave-private, k>=80 zero

    const int tid = threadIdx.x;
    const int wave = tid >> 6, lane = tid & 63;
    const int col = lane & 15, quad = lane >> 4;

    // stage shared B once per block (L2/L3-hot after first touch)
    for (int i = tid; i < 2560; i += 256) {          // 80*256/8 short8 chunks
        int h = i >> 5, k0 = (i & 31) * 8;
        *(short8*)&Bs[h][k0] = *(const short8*)(Bg + (h << 8) + k0);
    }
    if (tid < 192) {                                  // zero h0t k-tail 80..103
        int w = tid / 48, rem = tid % 48, row = rem / 3, c = 80 + (rem % 3) * 8;
        *(short8*)&h0t[w][row][c] = (short8)0;
    }
    __syncthreads();                                  // only barrier in kernel

    // hoisted per-lane constants
    short8 w1f[3][3];
    #pragma unroll
    for (int ks = 0; ks < 3; ++ks)
        #pragma unroll
        for (int nt = 0; nt < 3; ++nt)
            w1f[ks][nt] = *(const short8*)(w1t + (nt * 16 + col) * 96 + ks * 32 + quad * 8);
    float b1r[3], w2r[3];
    #pragma unroll
    for (int nt = 0; nt < 3; ++nt) {
        int h = nt * 16 + col;
        b1r[nt] = (h < H1_) ? b1[h] : 0.f;
        w2r[nt] = (h < H1_) ? W2[h] : 0.f;
    }
    const float b2v = b2[0];

    const int wid = blockIdx.x * 4 + wave;            // 0..4095

    for (int it = 0; it < 7; ++it) {
        const int tile = wid * 7 + it;
        if (tile >= NT_) break;
        const int row = tile * 16 + col;              // global row, exact (no tail)
        const int bl  = row / 200u;
        const float* ap = hist + (size_t)row * D_ + quad * 8;
        const float* tp = tgt + (size_t)bl * D_ + quad * 8;

        floatx4 A[8], T[8];
        #pragma unroll
        for (int u = 0; u < 8; ++u) A[u] = *(const floatx4*)(ap + (u >> 1) * 32 + (u & 1) * 4);
        #pragma unroll
        for (int u = 0; u < 8; ++u) T[u] = *(const floatx4*)(tp + (u >> 1) * 32 + (u & 1) * 4);

        // per-row bias rows (b can straddle inside a tile; branch is wave-uniform)
        const int rowq = tile * 16 + quad * 4;
        float beffr[5][4];
        {
            int bq0 = rowq / 200u, bq3 = (rowq + 3) / 200u;
            if (bq0 == bq3) {
                #pragma unroll
                for (int nt = 0; nt < 5; ++nt) {
                    float v = beff2[(size_t)bq0 * H0_ + nt * 16 + col];
                    #pragma unroll
                    for (int r = 0; r < 4; ++r) beffr[nt][r] = v;
                }
            } else {
                #pragma unroll
                for (int r = 0; r < 4; ++r) {
                    int br = (rowq + r) / 200u;
                    #pragma unroll
                    for (int nt = 0; nt < 5; ++nt)
                        beffr[nt][r] = beff2[(size_t)br * H0_ + nt * 16 + col];
                }
            }
        }

        // pack A-frags: hist and hist.*tgt
        short8 ah[4], ag[4];
        #pragma unroll
        for (int ks = 0; ks < 4; ++ks) {
            short8 h8, g8;
            #pragma unroll
            for (int j = 0; j < 8; ++j) {
                float hv = A[2 * ks + (j >> 2)][j & 3];
                float tv = T[2 * ks + (j >> 2)][j & 3];
                h8[j] = f2bf(hv);
                g8[j] = f2bf(hv * tv);
            }
            ah[ks] = h8; ag[ks] = g8;
        }

        // layer 0: K=256 (128 hist + 128 prod), B-frags from shared LDS
        floatx4 c0[5];
        #pragma unroll
        for (int nt = 0; nt < 5; ++nt) c0[nt] = (floatx4)0.f;
        #pragma unroll
        for (int ks = 0; ks < 4; ++ks)
            #pragma unroll
            for (int nt = 0; nt < 5; ++nt) {
                short8 bfr = *(const short8*)&Bs[nt * 16 + col][ks * 32 + quad * 8];
                c0[nt] = __builtin_amdgcn_mfma_f32_16x16x32_bf16(ah[ks], bfr, c0[nt], 0, 0, 0);
            }
        #pragma unroll
        for (int ks = 0; ks < 4; ++ks)
            #pragma unroll
            for (int nt = 0; nt < 5; ++nt) {
                short8 bfr = *(const short8*)&Bs[nt * 16 + col][128 + ks * 32 + quad * 8];
                c0[nt] = __builtin_amdgcn_mfma_f32_16x16x32_bf16(ag[ks], bfr, c0[nt], 0, 0, 0);
            }

        // bias+relu -> wave-private h0 tile (A-operand layout via LDS)
        #pragma unroll
        for (int nt = 0; nt < 5; ++nt)
            #pragma unroll
            for (int r = 0; r < 4; ++r) {
                float v = c0[nt][r] + beffr[nt][r];
                v = v > 0.f ? v : 0.f;
                h0t[wave][quad * 4 + r][nt * 16 + col] = f2bf(v);
            }

        // layer 1 (w1 frags in regs)
        floatx4 c1[3];
        #pragma unroll
        for (int nt = 0; nt < 3; ++nt) c1[nt] = (floatx4)0.f;
        #pragma unroll
        for (int ks = 0; ks < 3; ++ks) {
            short8 a1 = *(const short8*)&h0t[wave][col][ks * 32 + quad * 8];
            #pragma unroll
            for (int nt = 0; nt < 3; ++nt)
                c1[nt] = __builtin_amdgcn_mfma_f32_16x16x32_bf16(a1, w1f[ks][nt], c1[nt], 0, 0, 0);
        }

        // layer 2 + 16-lane reduce + store scores (attn slot is flat row index)
        float s4[4] = {0.f, 0.f, 0.f, 0.f};
        #pragma unroll
        for (int nt = 0; nt < 3; ++nt)
            #pragma unroll
            for (int r = 0; r < 4; ++r) {
                float v = c1[nt][r] + b1r[nt];
                v = v > 0.f ? v : 0.f;
                s4[r] += v * w2r[nt];
            }
        #pragma unroll
        for (int r = 0; r < 4; ++r) {
            s4[r] += __shfl_xor(s4[r], 1, 16);
            s4[r] += __shfl_xor(s4[r], 2, 16);
            s4[r] += __shfl_xor(s4[r], 4, 16);
            s4[r] += __shfl_xor(s4[r], 8, 16);
        }
        if (col == 0) {
            #pragma unroll
            for (int r = 0; r < 4; ++r)
                out[(size_t)B_ * D_ + rowq + r] = s4[r] + b2v;
        }
    }
}

// ---------------- softmax + weighted sum (streaming, full occupancy) --------
__global__ __launch_bounds__(256, 8) void attn_kernel(
    const float* __restrict__ hist, const int* __restrict__ mask,
    float* __restrict__ out)
{
    __shared__ float attns[L_];
    __shared__ float red[8];
    __shared__ float p0[D_];
    __shared__ float p1[D_];

    const int tid = threadIdx.x;
    const int b   = blockIdx.x;
    float* attn_out = out + (size_t)B_ * D_ + (size_t)b * L_;  // holds scores
    float* ui_out   = out + (size_t)b * D_;

    float sc = -3.0e38f;
    if (tid < L_) {
        sc = attn_out[tid];
        if (mask[(size_t)b * L_ + tid] == 0) sc -= 1e9f;
    }
    float m = sc;
    #pragma unroll
    for (int off = 32; off >= 1; off >>= 1) m = fmaxf(m, __shfl_xor(m, off, 64));
    int wid = tid >> 6;
    if ((tid & 63) == 0) red[wid] = m;
    __syncthreads();
    m = fmaxf(fmaxf(red[0], red[1]), fmaxf(red[2], red[3]));
    float e = (tid < L_) ? __expf(sc - m) : 0.f;
    float s = e;
    #pragma unroll
    for (int off = 32; off >= 1; off >>= 1) s += __shfl_xor(s, off, 64);
    if ((tid & 63) == 0) red[4 + wid] = s;
    __syncthreads();
    s = red[4] + red[5] + red[6] + red[7];
    float inv = 1.0f / s;
    float av = e * inv;
    if (tid < L_) {
        attns[tid] = av;
        attn_out[tid] = av;
    }
    __syncthreads();

    const int half = tid >> 7, d = tid & 127;
    const float* hb = hist + ((size_t)b * L_ + half * 100) * D_ + d;
    float acc = 0.f;
    #pragma unroll 25
    for (int l = 0; l < 100; ++l)
        acc = fmaf(attns[half * 100 + l], hb[(size_t)l * D_], acc);
    if (half) p1[d] = acc; else p0[d] = acc;
    __syncthreads();
    if (tid < D_) ui_out[tid] = p0[tid] + p1[tid];
}

extern "C" void kernel_launch(void* const* d_in, const int* in_sizes, int n_in,
                              void* d_out, int out_size, void* d_ws, size_t ws_size,
                              hipStream_t stream) {
    const float* hist = (const float*)d_in[0];
    const float* tgt  = (const float*)d_in[1];
    const int*   mask = (const int*)d_in[2];
    const float* W0   = (const float*)d_in[3];
    const float* b0   = (const float*)d_in[4];
    const float* W1   = (const float*)d_in[5];
    const float* b1   = (const float*)d_in[6];
    const float* W2   = (const float*)d_in[7];
    const float* b2   = (const float*)d_in[8];

    short* Bg    = (short*)d_ws;
    short* w1t   = (short*)d_ws + W1T_SOFF;
    float* beff2 = (float*)d_ws + BEFF_FOFF;

    prep_kernel<<<256, 256, 0, stream>>>(tgt, W0, b0, W1, Bg, w1t, beff2);
    score_kernel<<<1024, 256, 0, stream>>>(hist, tgt, Bg, w1t, beff2, b1, W2, b2,
                                           (float*)d_out);
    attn_kernel<<<B_, 256, 0, stream>>>(hist, mask, (float*)d_out);
}